// Round 3
// baseline (128.835 us; speedup 1.0000x reference)
//
#include <hip/hip_runtime.h>

typedef __bf16 bf16x8 __attribute__((ext_vector_type(8)));
typedef __bf16 bf16x4 __attribute__((ext_vector_type(4)));
typedef __bf16 bf16x2 __attribute__((ext_vector_type(2)));
typedef float  f32x4  __attribute__((ext_vector_type(4)));

// CK-pattern async global->LDS (16B per lane, wave-uniform LDS base).
__device__ __forceinline__ void gload_lds16(const void* g, void* l) {
    auto gp = reinterpret_cast<const __attribute__((address_space(1))) unsigned int*>(
        reinterpret_cast<uintptr_t>(g));
    auto lp = reinterpret_cast<__attribute__((address_space(3))) unsigned int*>(
        reinterpret_cast<uintptr_t>(l));
    __builtin_amdgcn_global_load_lds(gp, lp, 16, 0, 0);
}

// ---------------------------------------------------------------------------
// f32 -> bf16 elementwise (8 elems/thread)
// ---------------------------------------------------------------------------
__global__ __launch_bounds__(256) void convert_to_bf16(
    const float* __restrict__ src, __bf16* __restrict__ dst, int n8)
{
    const int i = blockIdx.x * 256 + threadIdx.x;
    if (i < n8) {
        f32x4 a = ((const f32x4*)src)[2 * i];
        f32x4 b = ((const f32x4*)src)[2 * i + 1];
        bf16x8 o;
        #pragma unroll
        for (int j = 0; j < 4; ++j) { o[j] = (__bf16)a[j]; o[4 + j] = (__bf16)b[j]; }
        ((bf16x8*)dst)[i] = o;
    }
}

// ---------------------------------------------------------------------------
// Prep: transpose f32 [R][C] -> bf16 [C][R]  (for MFMA B^T operands)
// ---------------------------------------------------------------------------
__global__ __launch_bounds__(256) void transpose_to_bf16(
    const float* __restrict__ src, __bf16* __restrict__ dst, int R, int C)
{
    __shared__ float tile[32][33];
    const int tx = threadIdx.x & 31, ty = threadIdx.x >> 5;
    const int r0 = blockIdx.y * 32, c0 = blockIdx.x * 32;
    #pragma unroll
    for (int i = ty; i < 32; i += 8)
        tile[i][tx] = src[(size_t)(r0 + i) * C + c0 + tx];
    __syncthreads();
    #pragma unroll
    for (int i = ty; i < 32; i += 8)
        dst[(size_t)(c0 + i) * R + r0 + tx] = (__bf16)tile[tx][i];
}

// ---------------------------------------------------------------------------
// m97-structure GEMM: Out[M][N] = op(A[M][K] @ B + bias), A bf16 [M][K],
// BT bf16 [N][K].  128x128 tile, BK=32, 4 waves (2x2), acc 4x4, LDS linear
// via global_load_lds width-16, 2 barriers per K-step.
// ---------------------------------------------------------------------------
template<bool RELU, bool OBF16>
__global__ __launch_bounds__(256) void gemm_lds(
    const __bf16* __restrict__ A, const __bf16* __restrict__ BT,
    const float* __restrict__ bias, void* __restrict__ Outp,
    int M, int N, int K)
{
    __shared__ __bf16 As[128][32];
    __shared__ __bf16 Bs[128][32];

    const int tid = threadIdx.x, lane = tid & 63, w = tid >> 6;
    const int wm = w >> 1, wn = w & 1;
    const int m0 = blockIdx.y * 128, n0 = blockIdx.x * 128;
    const int r = lane & 15, g = lane >> 4;

    const int srow = lane >> 2;            // 0..15
    const int scol = (lane & 3) * 8;       // element offset (16B)
    const __bf16* gA = A  + (size_t)(m0 + 32 * w + srow) * K + scol;
    const __bf16* gB = BT + (size_t)(n0 + 32 * w + srow) * K + scol;

    f32x4 acc[4][4];
    const f32x4 zero = {0.f, 0.f, 0.f, 0.f};
    #pragma unroll
    for (int mi = 0; mi < 4; ++mi)
        #pragma unroll
        for (int ni = 0; ni < 4; ++ni) acc[mi][ni] = zero;

    for (int k0 = 0; k0 < K; k0 += 32) {
        __syncthreads();
        gload_lds16(gA + k0,          &As[32 * w][0]);
        gload_lds16(gA + 16 * K + k0, &As[32 * w + 16][0]);
        gload_lds16(gB + k0,          &Bs[32 * w][0]);
        gload_lds16(gB + 16 * K + k0, &Bs[32 * w + 16][0]);
        __syncthreads();

        bf16x8 af[4], bfr[4];
        #pragma unroll
        for (int mi = 0; mi < 4; ++mi)
            af[mi] = *(const bf16x8*)&As[wm * 64 + mi * 16 + r][g * 8];
        #pragma unroll
        for (int ni = 0; ni < 4; ++ni)
            bfr[ni] = *(const bf16x8*)&Bs[wn * 64 + ni * 16 + r][g * 8];
        #pragma unroll
        for (int mi = 0; mi < 4; ++mi)
            #pragma unroll
            for (int ni = 0; ni < 4; ++ni)
                acc[mi][ni] = __builtin_amdgcn_mfma_f32_16x16x32_bf16(
                    af[mi], bfr[ni], acc[mi][ni], 0, 0, 0);
    }

    const int orow = m0 + wm * 64 + g * 4;
    const int ocol = n0 + wn * 64 + r;
    #pragma unroll
    for (int ni = 0; ni < 4; ++ni) {
        const float bb = bias[ocol + ni * 16];
        #pragma unroll
        for (int mi = 0; mi < 4; ++mi) {
            #pragma unroll
            for (int q = 0; q < 4; ++q) {
                float v = acc[mi][ni][q] + bb;
                if constexpr (RELU) v = fmaxf(v, 0.f);
                const size_t o = (size_t)(orow + mi * 16 + q) * N + ocol + ni * 16;
                if constexpr (OBF16) ((__bf16*)Outp)[o] = (__bf16)v;
                else                 ((float*)Outp)[o]  = v;
            }
        }
    }
}

// ---------------------------------------------------------------------------
// Fused memory attention (MFMA).  1 wave = 1 token, wave-private LDS, no
// barriers.  Register-prefetches next chunk's mem (T14 issue-early); addr is
// bf16 (L1-resident 16KB).
// ---------------------------------------------------------------------------
__device__ __forceinline__ int kbyte(int m, int e) {
    return m * 128 + ((((e >> 3) ^ (m & 7))) << 4) + (e & 7) * 2;
}

__global__ __launch_bounds__(256, 4) void memory_attn_mfma(
    const __bf16* __restrict__ Q,      // [N][512] bf16 (relu'd q proj)
    const float*  __restrict__ mem,    // [N][128][64] f32
    const __bf16* __restrict__ adrb,   // [128][64] bf16
    __bf16* __restrict__ attn)         // [N][512] bf16
{
    __shared__ __align__(16) unsigned char kbuf[4][4096];   // k: 32 x 128B swizzled
    __shared__ __align__(16) unsigned char tbuf[4][5120];   // memT: 64 x 80B
    __shared__ float denl[4][8];

    const int tid = threadIdx.x, lane = tid & 63, w = tid >> 6;
    const int n = blockIdx.x * 4 + w;
    const int v = lane & 15, g = lane >> 4;
    const int e4 = 4 * v;

    unsigned char* kb = kbuf[w];
    unsigned char* tb = tbuf[w];
    const float* pmem = mem + (size_t)n * 128 * 64;

    // q fragments (stage-A B-operand): lane holds q[h=v][d = 32*kst + 8g .. +8]
    const __bf16* qp = Q + (size_t)n * 512 + v * 64 + 8 * g;
    const bf16x8 qf0 = *(const bf16x8*)(qp);
    const bf16x8 qf1 = *(const bf16x8*)(qp + 32);

    f32x4 acc[4];
    const f32x4 zero = {0.f, 0.f, 0.f, 0.f};
    #pragma unroll
    for (int nb = 0; nb < 4; ++nb) acc[nb] = zero;
    float psum = 0.f;

    // preload chunk 0 mem
    f32x4 cm[8];
    #pragma unroll
    for (int i = 0; i < 4; ++i) {
        const int mo = 8 * i + 2 * g;
        cm[2 * i]     = *(const f32x4*)(pmem + (size_t)mo * 64 + e4);
        cm[2 * i + 1] = *(const f32x4*)(pmem + (size_t)(mo + 1) * 64 + e4);
    }

    #pragma unroll
    for (int c = 0; c < 4; ++c) {
        const int mb = c * 32;
        // ---- prefetch next chunk's mem into regs (issue-early) ----
        f32x4 nm[8];
        if (c < 3) {
            #pragma unroll
            for (int i = 0; i < 4; ++i) {
                const int mo = mb + 32 + 8 * i + 2 * g;
                nm[2 * i]     = *(const f32x4*)(pmem + (size_t)mo * 64 + e4);
                nm[2 * i + 1] = *(const f32x4*)(pmem + (size_t)(mo + 1) * 64 + e4);
            }
        }
        // ---- stage chunk c from cm ----
        #pragma unroll
        for (int i = 0; i < 4; ++i) {
            const int mo = mb + 8 * i + 2 * g;
            const bf16x4 a0 = *(const bf16x4*)(adrb + (size_t)(mo & 127) * 64 + e4);
            const bf16x4 a1 = *(const bf16x4*)(adrb + (size_t)((mo + 1) & 127) * 64 + e4);
            const f32x4 m0 = cm[2 * i], m1 = cm[2 * i + 1];
            bf16x4 k0, k1;
            #pragma unroll
            for (int j = 0; j < 4; ++j) {
                k0[j] = (__bf16)fmaxf(m0[j] + (float)a0[j], 0.f);
                k1[j] = (__bf16)fmaxf(m1[j] + (float)a1[j], 0.f);
            }
            const int mo_l = mo & 31;                   // row within chunk
            *(bf16x4*)(kb + kbyte(mo_l,     e4)) = k0;
            *(bf16x4*)(kb + kbyte(mo_l + 1, e4)) = k1;
            const int kap = 8 * ((mo_l >> 2) & 3) + 4 * (mo_l >> 4) + (mo_l & 3);
            #pragma unroll
            for (int j2 = 0; j2 < 4; ++j2) {
                bf16x2 p = { (__bf16)m0[j2], (__bf16)m1[j2] };
                *(bf16x2*)(tb + (size_t)(e4 + j2) * 80 + kap * 2) = p;
            }
        }

        // ---- stage A: S^T = k . q^T ----
        f32x4 sA0 = zero, sA1 = zero;
        {
            const bf16x8 a00 = *(const bf16x8*)(kb + kbyte(v,      8 * g));
            const bf16x8 a01 = *(const bf16x8*)(kb + kbyte(v,      32 + 8 * g));
            const bf16x8 a10 = *(const bf16x8*)(kb + kbyte(v + 16, 8 * g));
            const bf16x8 a11 = *(const bf16x8*)(kb + kbyte(v + 16, 32 + 8 * g));
            sA0 = __builtin_amdgcn_mfma_f32_16x16x32_bf16(a00, qf0, sA0, 0, 0, 0);
            sA0 = __builtin_amdgcn_mfma_f32_16x16x32_bf16(a01, qf1, sA0, 0, 0, 0);
            sA1 = __builtin_amdgcn_mfma_f32_16x16x32_bf16(a10, qf0, sA1, 0, 0, 0);
            sA1 = __builtin_amdgcn_mfma_f32_16x16x32_bf16(a11, qf1, sA1, 0, 0, 0);
        }
        psum += sA0[0] + sA0[1] + sA0[2] + sA0[3]
              + sA1[0] + sA1[1] + sA1[2] + sA1[3];

        bf16x8 pa;
        #pragma unroll
        for (int q = 0; q < 4; ++q) {
            pa[q]     = (__bf16)sA0[q];
            pa[4 + q] = (__bf16)sA1[q];
        }

        // ---- stage B: num += S . mem ----
        #pragma unroll
        for (int nb = 0; nb < 4; ++nb) {
            const bf16x8 bf = *(const bf16x8*)(tb + (size_t)(16 * nb + v) * 80 + 16 * g);
            acc[nb] = __builtin_amdgcn_mfma_f32_16x16x32_bf16(pa, bf, acc[nb], 0, 0, 0);
        }

        if (c < 3) {
            #pragma unroll
            for (int t = 0; t < 8; ++t) cm[t] = nm[t];
        }
    }

    // ---- epilogue ----
    psum += __shfl_xor(psum, 16);
    psum += __shfl_xor(psum, 32);
    if (lane < 8) denl[w][lane] = psum;

    if (g < 2) {
        const f32x4 d4 = *(const f32x4*)&denl[w][4 * g];
        float inv[4];
        #pragma unroll
        for (int q = 0; q < 4; ++q) inv[q] = 1.f / (d4[q] + 1e-5f);
        #pragma unroll
        for (int nb = 0; nb < 4; ++nb) {
            #pragma unroll
            for (int q = 0; q < 4; ++q) {
                attn[(size_t)n * 512 + (4 * g + q) * 64 + 16 * nb + v] =
                    (__bf16)(acc[nb][q] * inv[q]);
            }
        }
    }
}

// ---------------------------------------------------------------------------
extern "C" void kernel_launch(void* const* d_in, const int* in_sizes, int n_in,
                              void* d_out, int out_size, void* d_ws, size_t ws_size,
                              hipStream_t stream)
{
    const float* query     = (const float*)d_in[0];
    const float* addresses = (const float*)d_in[1];
    const float* memories  = (const float*)d_in[2];
    const float* Wq        = (const float*)d_in[3];
    const float* bq        = (const float*)d_in[4];
    const float* Wo        = (const float*)d_in[5];
    const float* bo        = (const float*)d_in[6];
    float* out = (float*)d_out;

    char* ws = (char*)d_ws;
    __bf16* WqT  = (__bf16*)(ws);                      // [512][1024]  1 MB
    __bf16* WoT  = (__bf16*)(ws + (1 << 20));          // [1024][512]  1 MB
    __bf16* Qb   = (__bf16*)(ws + (2 << 20));          // [8192][512]  8 MB
    __bf16* Ab   = (__bf16*)(ws + (10 << 20));         // [8192][512]  8 MB
    __bf16* Adrb = (__bf16*)(ws + (18 << 20));         // [128][64]    16 KB
    __bf16* Qbf  = (__bf16*)d_out;                     // [8192][1024] 16 MB, stashed
                                                       // in d_out, overwritten later

    convert_to_bf16<<<4096, 256, 0, stream>>>(query, Qbf, 8192 * 1024 / 8);
    convert_to_bf16<<<4, 256, 0, stream>>>(addresses, Adrb, 128 * 64 / 8);
    transpose_to_bf16<<<dim3(512 / 32, 1024 / 32), 256, 0, stream>>>(Wq, WqT, 1024, 512);
    transpose_to_bf16<<<dim3(1024 / 32, 512 / 32), 256, 0, stream>>>(Wo, WoT, 512, 1024);

    // Q = relu(query @ Wq + bq)  -> bf16 [8192][512]
    gemm_lds<true, true><<<dim3(512 / 128, 8192 / 128), 256, 0, stream>>>(
        Qbf, WqT, bq, Qb, 8192, 512, 1024);

    // fused per-token linear memory read (MFMA) -> attn bf16 [8192][512]
    memory_attn_mfma<<<dim3(8192 / 4), 256, 0, stream>>>(Qb, memories, Adrb, Ab);

    // out = attn @ Wo + bo  -> f32 [8192][1024]
    gemm_lds<false, false><<<dim3(1024 / 128, 8192 / 128), 256, 0, stream>>>(
        Ab, WoT, bo, out, 8192, 1024, 512);
}